// Round 5
// baseline (296.312 us; speedup 1.0000x reference)
//
#include <hip/hip_runtime.h>
#include <math.h>

#define B_SZ 2048
#define N_SZ 4096
#define D_SZ 512
#define INV_T 14.285714285714286f
#define KC 0.3989422804014327f

typedef __bf16 bf16x8 __attribute__((ext_vector_type(8)));
typedef __bf16 bf16x2 __attribute__((ext_vector_type(2)));
typedef float f32x4 __attribute__((ext_vector_type(4)));

// feats row i (view-major concat): v = i>>11, b = i&2047, src row = b*2+v
__device__ __forceinline__ long long frow(int i) {
    return (long long)(((i & (B_SZ - 1)) << 1) | (i >> 11)) * D_SZ;
}

// ---------------- Kernel 1: prep = conv + sort + zero-init (one dispatch) ----
// blocks 0..4095: fp32->bf16 row conv (+ blocks 0..48 zero accs/counter)
// blocks 4096..4103: counting-sort of labels + per-label global ranks
__global__ __launch_bounds__(256) void prep_kernel(const float* __restrict__ feats,
                                                   const float* __restrict__ labels,
                                                   __bf16* __restrict__ Hp,
                                                   float* __restrict__ sorted,
                                                   unsigned short* __restrict__ lo,
                                                   unsigned short* __restrict__ hi,
                                                   float* __restrict__ accz,
                                                   unsigned int* __restrict__ cnt) {
    __shared__ float lv[B_SZ];
    const int bid = blockIdx.x;
    const int t = threadIdx.x;
    if (bid < N_SZ) {
        const float2 v = *reinterpret_cast<const float2*>(&feats[frow(bid) + 2 * t]);
        bf16x2 hh = {(__bf16)v.x, (__bf16)v.y};
        *reinterpret_cast<bf16x2*>(&Hp[(size_t)bid * D_SZ + 2 * t]) = hh;
        if (bid < 48) accz[bid * 256 + t] = 0.f;
        if (bid == 48 && t == 0) *cnt = 0u;
        return;
    }
    // ---- sort section ----
#pragma unroll
    for (int s = 0; s < 8; ++s) lv[t + 256 * s] = labels[t + 256 * s];
    const int a = (bid - N_SZ) * 256 + t;
    const float la = labels[a];
    __syncthreads();
    int lt = 0, le = 0, tlo = 0;
    for (int c4 = 0; c4 < B_SZ / 4; ++c4) {
        float4 v = reinterpret_cast<const float4*>(lv)[c4];
        const float vv[4] = {v.x, v.y, v.z, v.w};
#pragma unroll
        for (int e = 0; e < 4; ++e) {
            lt += (vv[e] < la) ? 1 : 0;
            le += (vv[e] <= la) ? 1 : 0;
            tlo += (vv[e] == la && (4 * c4 + e) < a) ? 1 : 0;
        }
    }
    sorted[lt + tlo] = la;
    lo[a] = (unsigned short)lt;
    hi[a] = (unsigned short)le;
}

// ---------------- Kernel 2: TRANSPOSED rank table, one binary search --------
// RkT[a][b] = B - #{c: |l_b-l_c| <= |l_b-l_a|}   (same verified formula as R3,
// block/thread roles swapped so lo[a]/hi[a] are block scalars and writes +
// the main-kernel epilogue reads are both coalesced)
__global__ __launch_bounds__(256) void rank_kernel(const float* __restrict__ labels,
                                                   const float* __restrict__ sorted,
                                                   const unsigned short* __restrict__ lo,
                                                   const unsigned short* __restrict__ hi,
                                                   unsigned short* __restrict__ RkT) {
    __shared__ float Ls[B_SZ];
    const int a = blockIdx.x;
    const int t = threadIdx.x;
#pragma unroll
    for (int s = 0; s < 8; ++s) Ls[t + 256 * s] = sorted[t + 256 * s];
    const float la = labels[a];
    const int loa = (int)lo[a];
    const int hia = (int)hi[a];
    float x[8];
    int p[8];
    bool inc[8];
#pragma unroll
    for (int s = 0; s < 8; ++s) {
        const float lb = labels[t + 256 * s];
        const float ts = fabsf(lb - la);
        inc[s] = (la <= lb);
        x[s] = inc[s] ? (lb + ts) : (lb - ts);
        p[s] = 0;
    }
    __syncthreads();
#pragma unroll
    for (int step = B_SZ; step; step >>= 1) {
#pragma unroll
        for (int s = 0; s < 8; ++s) {
            const unsigned q = (unsigned)(p[s] + step - 1);
            const float Lq = Ls[q & (B_SZ - 1)];
            const bool cond = (Lq < x[s]) || (Lq == x[s] && inc[s]);
            if (q < B_SZ && cond) p[s] += step;
        }
    }
#pragma unroll
    for (int s = 0; s < 8; ++s) {
        const int inner = inc[s] ? (p[s] - loa) : (hia - p[s]);
        RkT[(size_t)a * B_SZ + t + 256 * s] = (unsigned short)(B_SZ - inner);
    }
}

// ---------------- Kernel 3: MFMA GEMM from L2 (no LDS) + epilogue + finish --
// 128x128 per block, 4 waves of 64x64. Fragments loaded straight from global
// (L2-resident 4 MB panel) — zero barriers in the K-loop.
__global__ __launch_bounds__(256, 3) void main_kernel(const __bf16* __restrict__ Hp,
                                                      const float* __restrict__ labels,
                                                      const unsigned short* __restrict__ RkT,
                                                      float* __restrict__ Uacc,
                                                      float* __restrict__ Wacc,
                                                      float* __restrict__ PSacc,
                                                      unsigned int* __restrict__ cnt,
                                                      float* __restrict__ out) {
    __shared__ int isLast;
    __shared__ float red[4];

    const int t = threadIdx.x;
    const int w = t >> 6;
    const int l = t & 63;
    const int lr = l & 15;
    const int quad = l >> 4;
    const int wy = w >> 1, wx = w & 1;
    const int it = blockIdx.y * 128, jt = blockIdx.x * 128;

    // m91-verified NT fragment source: lane reads row (base+lr), k = quad*8..+7
    const __bf16* Abase = Hp + (size_t)(it + wy * 64 + lr) * D_SZ + quad * 8;
    const __bf16* Bbase = Hp + (size_t)(jt + wx * 64 + lr) * D_SZ + quad * 8;

    f32x4 acc[4][4];
#pragma unroll
    for (int mi = 0; mi < 4; ++mi)
#pragma unroll
        for (int nj = 0; nj < 4; ++nj) acc[mi][nj] = {0.f, 0.f, 0.f, 0.f};

#pragma unroll 4
    for (int kt = 0; kt < D_SZ / 32; ++kt) {
        const int k0 = kt * 32;
        bf16x8 af[4], bfr[4];
#pragma unroll
        for (int x = 0; x < 4; ++x) {
            af[x] = *reinterpret_cast<const bf16x8*>(Abase + (size_t)x * 16 * D_SZ + k0);
            bfr[x] = *reinterpret_cast<const bf16x8*>(Bbase + (size_t)x * 16 * D_SZ + k0);
        }
#pragma unroll
        for (int mi = 0; mi < 4; ++mi)
#pragma unroll
            for (int nj = 0; nj < 4; ++nj)
                acc[mi][nj] = __builtin_amdgcn_mfma_f32_16x16x32_bf16(af[mi], bfr[nj], acc[mi][nj], 0, 0, 0);
    }

    // --- fused epilogue: D[row=quad*4+reg][col=lr] ---
    float rw[16], rp[16], ru[16];
#pragma unroll
    for (int x = 0; x < 16; ++x) { rw[x] = 0.f; rp[x] = 0.f; ru[x] = 0.f; }

    float lis[16];
#pragma unroll
    for (int mi = 0; mi < 4; ++mi)
#pragma unroll
        for (int reg = 0; reg < 4; ++reg)
            lis[mi * 4 + reg] = labels[(it + wy * 64 + mi * 16 + quad * 4 + reg) & (B_SZ - 1)];

#pragma unroll
    for (int nj = 0; nj < 4; ++nj) {
        const int j_g = jt + wx * 64 + nj * 16 + lr;
        const int jb = j_g & (B_SZ - 1);
        const float lj = labels[jb];
#pragma unroll
        for (int mi = 0; mi < 4; ++mi) {
#pragma unroll
            for (int reg = 0; reg < 4; ++reg) {
                const int i_g = it + wy * 64 + mi * 16 + quad * 4 + reg;
                const int ib = i_g & (B_SZ - 1);
                // coalesced: 16 lanes (lr) -> 16 consecutive jb in row ib
                const float rkv = (float)RkT[(size_t)ib * B_SZ + jb];
                if (i_g != j_g) {
                    const float s = acc[mi][nj][reg] * INV_T;
                    const float dl = lis[mi * 4 + reg] - lj;
                    const float msk = __expf(dl * dl * (-0.5f)) * KC;
                    const int xx = mi * 4 + reg;
                    rw[xx] += msk;
                    rp[xx] = fmaf(msk, s, rp[xx]);
                    ru[xx] = fmaf(__expf(s - INV_T), 2.0f * rkv, ru[xx]);
                }
            }
        }
    }

#pragma unroll
    for (int xx = 0; xx < 16; ++xx) {
        float a = rw[xx], b = rp[xx], c = ru[xx];
#pragma unroll
        for (int off = 8; off >= 1; off >>= 1) {
            a += __shfl_xor(a, off, 16);
            b += __shfl_xor(b, off, 16);
            c += __shfl_xor(c, off, 16);
        }
        if (lr == 0) {
            const int mi = xx >> 2, reg = xx & 3;
            const int row = it + wy * 64 + mi * 16 + quad * 4 + reg;
            atomicAdd(&Wacc[row], a);
            atomicAdd(&PSacc[row], b);
            atomicAdd(&Uacc[row], c);
        }
    }

    // --- last block performs the final reduction (saves a dispatch) ---
    __threadfence();
    if (t == 0) {
        unsigned int old = atomicAdd(cnt, 1u);
        isLast = (old == (unsigned)(gridDim.x * gridDim.y - 1)) ? 1 : 0;
    }
    __syncthreads();
    if (isLast) {
        __threadfence();
        float sum = 0.f;
        for (int r2 = t; r2 < N_SZ; r2 += 256) {
            const float u = __hip_atomic_load(&Uacc[r2], __ATOMIC_RELAXED, __HIP_MEMORY_SCOPE_AGENT);
            const float ww = __hip_atomic_load(&Wacc[r2], __ATOMIC_RELAXED, __HIP_MEMORY_SCOPE_AGENT);
            const float ps = __hip_atomic_load(&PSacc[r2], __ATOMIC_RELAXED, __HIP_MEMORY_SCOPE_AGENT);
            sum += ps / ww - INV_T - logf(u);
        }
#pragma unroll
        for (int off = 32; off >= 1; off >>= 1) sum += __shfl_xor(sum, off, 64);
        if ((t & 63) == 0) red[t >> 6] = sum;
        __syncthreads();
        if (t == 0) out[0] = -(red[0] + red[1] + red[2] + red[3]) / (float)N_SZ;
    }
}

extern "C" void kernel_launch(void* const* d_in, const int* in_sizes, int n_in,
                              void* d_out, int out_size, void* d_ws, size_t ws_size,
                              hipStream_t stream) {
    const float* feats = (const float*)d_in[0];
    const float* labels = (const float*)d_in[1];
    float* out = (float*)d_out;

    char* ws = (char*)d_ws;
    __bf16* Hp = (__bf16*)ws;                                   // 4 MB (16B-aligned)
    unsigned short* RkT = (unsigned short*)(ws + (size_t)N_SZ * D_SZ * 2);  // 8 MB
    float* Uacc = (float*)((char*)RkT + (size_t)B_SZ * B_SZ * 2);
    float* Wacc = Uacc + N_SZ;
    float* PSacc = Wacc + N_SZ;
    float* sorted = PSacc + N_SZ;
    unsigned short* lo = (unsigned short*)(sorted + B_SZ);
    unsigned short* hi = lo + B_SZ;
    unsigned int* cnt = (unsigned int*)(hi + B_SZ);

    prep_kernel<<<dim3(N_SZ + 8), dim3(256), 0, stream>>>(feats, labels, Hp, sorted, lo, hi, Uacc, cnt);
    rank_kernel<<<dim3(B_SZ), dim3(256), 0, stream>>>(labels, sorted, lo, hi, RkT);
    main_kernel<<<dim3(32, 32), dim3(256), 0, stream>>>(Hp, labels, RkT, Uacc, Wacc, PSacc, cnt, out);
}

// Round 6
// 273.243 us; speedup vs baseline: 1.0844x; 1.0844x over previous
//
#include <hip/hip_runtime.h>
#include <math.h>

#define B_SZ 2048
#define N_SZ 4096
#define D_SZ 512
#define INV_T 14.285714285714286f
#define KC 0.3989422804014327f
#define BK 32

typedef __bf16 bf16x8 __attribute__((ext_vector_type(8)));
typedef __bf16 bf16x2 __attribute__((ext_vector_type(2)));
typedef float f32x4 __attribute__((ext_vector_type(4)));

// feats row i (view-major concat): v = i>>11, b = i&2047, src row = b*2+v
__device__ __forceinline__ long long frow(int i) {
    return (long long)(((i & (B_SZ - 1)) << 1) | (i >> 11)) * D_SZ;
}

// ---------------- Kernel 1: prep = conv + sort + zero-init (one dispatch) ----
__global__ __launch_bounds__(256) void prep_kernel(const float* __restrict__ feats,
                                                   const float* __restrict__ labels,
                                                   __bf16* __restrict__ Hp,
                                                   float* __restrict__ sorted,
                                                   unsigned short* __restrict__ lo,
                                                   unsigned short* __restrict__ hi,
                                                   float* __restrict__ accz,
                                                   unsigned int* __restrict__ cnt) {
    __shared__ float lv[B_SZ];
    const int bid = blockIdx.x;
    const int t = threadIdx.x;
    if (bid < N_SZ) {
        const float2 v = *reinterpret_cast<const float2*>(&feats[frow(bid) + 2 * t]);
        bf16x2 hh = {(__bf16)v.x, (__bf16)v.y};
        *reinterpret_cast<bf16x2*>(&Hp[(size_t)bid * D_SZ + 2 * t]) = hh;
        if (bid < 48) accz[bid * 256 + t] = 0.f;
        if (bid == 48 && t == 0) *cnt = 0u;
        return;
    }
    // ---- sort section (blocks N_SZ..N_SZ+7) ----
#pragma unroll
    for (int s = 0; s < 8; ++s) lv[t + 256 * s] = labels[t + 256 * s];
    const int a = (bid - N_SZ) * 256 + t;
    const float la = labels[a];
    __syncthreads();
    int lt = 0, le = 0, tlo = 0;
    for (int c4 = 0; c4 < B_SZ / 4; ++c4) {
        float4 v = reinterpret_cast<const float4*>(lv)[c4];
        const float vv[4] = {v.x, v.y, v.z, v.w};
#pragma unroll
        for (int e = 0; e < 4; ++e) {
            lt += (vv[e] < la) ? 1 : 0;
            le += (vv[e] <= la) ? 1 : 0;
            tlo += (vv[e] == la && (4 * c4 + e) < a) ? 1 : 0;
        }
    }
    sorted[lt + tlo] = la;
    lo[a] = (unsigned short)lt;
    hi[a] = (unsigned short)le;
}

// ---------------- Kernel 2: TRANSPOSED rank table, one binary search --------
// RkT[a][b] = B - #{c: |l_b-l_c| <= |l_b-l_a|}
__global__ __launch_bounds__(256) void rank_kernel(const float* __restrict__ labels,
                                                   const float* __restrict__ sorted,
                                                   const unsigned short* __restrict__ lo,
                                                   const unsigned short* __restrict__ hi,
                                                   unsigned short* __restrict__ RkT) {
    __shared__ float Ls[B_SZ];
    const int a = blockIdx.x;
    const int t = threadIdx.x;
#pragma unroll
    for (int s = 0; s < 8; ++s) Ls[t + 256 * s] = sorted[t + 256 * s];
    const float la = labels[a];
    const int loa = (int)lo[a];
    const int hia = (int)hi[a];
    float x[8];
    int p[8];
    bool inc[8];
#pragma unroll
    for (int s = 0; s < 8; ++s) {
        const float lb = labels[t + 256 * s];
        const float ts = fabsf(lb - la);
        inc[s] = (la <= lb);
        x[s] = inc[s] ? (lb + ts) : (lb - ts);
        p[s] = 0;
    }
    __syncthreads();
#pragma unroll
    for (int step = B_SZ; step; step >>= 1) {
#pragma unroll
        for (int s = 0; s < 8; ++s) {
            const unsigned q = (unsigned)(p[s] + step - 1);
            const float Lq = Ls[q & (B_SZ - 1)];
            const bool cond = (Lq < x[s]) || (Lq == x[s] && inc[s]);
            if (q < B_SZ && cond) p[s] += step;
        }
    }
#pragma unroll
    for (int s = 0; s < 8; ++s) {
        const int inner = inc[s] ? (p[s] - loa) : (hia - p[s]);
        RkT[(size_t)a * B_SZ + t + 256 * s] = (unsigned short)(B_SZ - inner);
    }
}

// ---------------- Kernel 3: MFMA bf16 GEMM (R3 K-loop) + epilogue + finish --
// 128x128 tile/block, 4 waves each 64x64 (4x4 of 16x16x32 mfma), S ~= H*H^T.
__global__ __launch_bounds__(256) void main_kernel(const __bf16* __restrict__ Hp,
                                                   const float* __restrict__ labels,
                                                   const unsigned short* __restrict__ RkT,
                                                   float* __restrict__ Uacc,
                                                   float* __restrict__ Wacc,
                                                   float* __restrict__ PSacc,
                                                   unsigned int* __restrict__ cnt,
                                                   float* __restrict__ out) {
    __shared__ __bf16 S[2][128 * BK];   // A, B : 8 KB each
    __shared__ float sli[128], slj[128];
    __shared__ int isLast;
    __shared__ float red[4];

    const int t = threadIdx.x;
    const int w = t >> 6;           // wave 0..3
    const int l = t & 63;
    const int it = blockIdx.y * 128;
    const int jt = blockIdx.x * 128;

    if (t < 128) sli[t] = labels[(it + t) & (B_SZ - 1)];
    else slj[t - 128] = labels[(jt + t - 128) & (B_SZ - 1)];

    // --- staging: wave w fills half (w&1) of tile (w>>1); 0=A(i) 1=B(j) ---
    const int tileidx = w >> 1;
    const int half = w & 1;
    const int tb = tileidx ? jt : it;
    const int gblk = (l & 3) ^ ((l >> 3) & 3);      // XOR-swizzled 16B block
    const __bf16* gbase = Hp + (size_t)(tb + half * 64 + (l >> 2)) * D_SZ + gblk * 8;
    __bf16* myTile = S[tileidx] + (half * 64) * BK;

    // --- fragment mapping (verified m91, NT GEMM) ---
    const int lr = l & 15;
    const int quad = l >> 4;
    const int swz = (lr >> 1) & 3;
    const int wy = w >> 1, wx = w & 1;
    const int aoff = (wy * 64 + lr) * BK + ((quad ^ swz) * 8);
    const int boff = (wx * 64 + lr) * BK + ((quad ^ swz) * 8);

    f32x4 acc[4][4];
#pragma unroll
    for (int mi = 0; mi < 4; ++mi)
#pragma unroll
        for (int nj = 0; nj < 4; ++nj) acc[mi][nj] = {0.f, 0.f, 0.f, 0.f};

    for (int kt = 0; kt < D_SZ / BK; ++kt) {
        __syncthreads();   // prior frag reads done (iter0: labels written)
        const __bf16* g = gbase + kt * BK;
#pragma unroll
        for (int q = 0; q < 4; ++q) {
            __builtin_amdgcn_global_load_lds(
                (const __attribute__((address_space(1))) void*)(g + (size_t)q * 16 * D_SZ),
                (__attribute__((address_space(3))) void*)(myTile + q * 16 * BK + l * 8),
                16, 0, 0);
        }
        __syncthreads();

        bf16x8 bh[4];
#pragma unroll
        for (int nj = 0; nj < 4; ++nj)
            bh[nj] = *reinterpret_cast<const bf16x8*>(&S[1][boff + nj * 16 * BK]);
#pragma unroll
        for (int mi = 0; mi < 4; ++mi) {
            bf16x8 ah = *reinterpret_cast<const bf16x8*>(&S[0][aoff + mi * 16 * BK]);
#pragma unroll
            for (int nj = 0; nj < 4; ++nj)
                acc[mi][nj] = __builtin_amdgcn_mfma_f32_16x16x32_bf16(ah, bh[nj], acc[mi][nj], 0, 0, 0);
        }
    }

    // --- fused epilogue: D[row=quad*4+reg][col=lr]; RkT reads coalesced ---
    float rw[16], rp[16], ru[16];
#pragma unroll
    for (int x = 0; x < 16; ++x) { rw[x] = 0.f; rp[x] = 0.f; ru[x] = 0.f; }

    const int jcol = wx * 64 + lr;
    const int irow0 = wy * 64 + quad * 4;
#pragma unroll
    for (int nj = 0; nj < 4; ++nj) {
        const int j_g = jt + jcol + nj * 16;
        const int jb = j_g & (B_SZ - 1);
        const float lj = slj[jcol + nj * 16];
#pragma unroll
        for (int mi = 0; mi < 4; ++mi) {
#pragma unroll
            for (int reg = 0; reg < 4; ++reg) {
                const int i_g = it + irow0 + mi * 16 + reg;
                const int ib = i_g & (B_SZ - 1);
                const float rkv = (float)RkT[(size_t)ib * B_SZ + jb];
                if (i_g != j_g) {
                    const float s = acc[mi][nj][reg] * INV_T;
                    const float dl = sli[irow0 + mi * 16 + reg] - lj;
                    const float msk = __expf(dl * dl * (-0.5f)) * KC;
                    const int xx = mi * 4 + reg;
                    rw[xx] += msk;
                    rp[xx] = fmaf(msk, s, rp[xx]);
                    ru[xx] = fmaf(__expf(s - INV_T), 2.0f * rkv, ru[xx]);
                }
            }
        }
    }

#pragma unroll
    for (int xx = 0; xx < 16; ++xx) {
        float a = rw[xx], b = rp[xx], c = ru[xx];
#pragma unroll
        for (int off = 8; off >= 1; off >>= 1) {
            a += __shfl_xor(a, off, 16);
            b += __shfl_xor(b, off, 16);
            c += __shfl_xor(c, off, 16);
        }
        if (lr == 0) {
            const int mi = xx >> 2, reg = xx & 3;
            const int row = it + irow0 + mi * 16 + reg;
            atomicAdd(&Wacc[row], a);
            atomicAdd(&PSacc[row], b);
            atomicAdd(&Uacc[row], c);
        }
    }

    // --- last block performs the final reduction ---
    __threadfence();
    if (t == 0) {
        unsigned int old = atomicAdd(cnt, 1u);
        isLast = (old == (unsigned)(gridDim.x * gridDim.y - 1)) ? 1 : 0;
    }
    __syncthreads();
    if (isLast) {
        __threadfence();
        float sum = 0.f;
        for (int r2 = t; r2 < N_SZ; r2 += 256) {
            const float u = __hip_atomic_load(&Uacc[r2], __ATOMIC_RELAXED, __HIP_MEMORY_SCOPE_AGENT);
            const float ww = __hip_atomic_load(&Wacc[r2], __ATOMIC_RELAXED, __HIP_MEMORY_SCOPE_AGENT);
            const float ps = __hip_atomic_load(&PSacc[r2], __ATOMIC_RELAXED, __HIP_MEMORY_SCOPE_AGENT);
            sum += ps / ww - INV_T - logf(u);
        }
#pragma unroll
        for (int off = 32; off >= 1; off >>= 1) sum += __shfl_xor(sum, off, 64);
        if ((t & 63) == 0) red[t >> 6] = sum;
        __syncthreads();
        if (t == 0) out[0] = -(red[0] + red[1] + red[2] + red[3]) / (float)N_SZ;
    }
}

extern "C" void kernel_launch(void* const* d_in, const int* in_sizes, int n_in,
                              void* d_out, int out_size, void* d_ws, size_t ws_size,
                              hipStream_t stream) {
    const float* feats = (const float*)d_in[0];
    const float* labels = (const float*)d_in[1];
    float* out = (float*)d_out;

    char* ws = (char*)d_ws;
    __bf16* Hp = (__bf16*)ws;                                   // 4 MB
    unsigned short* RkT = (unsigned short*)(ws + (size_t)N_SZ * D_SZ * 2);  // 8 MB
    float* Uacc = (float*)((char*)RkT + (size_t)B_SZ * B_SZ * 2);
    float* Wacc = Uacc + N_SZ;
    float* PSacc = Wacc + N_SZ;
    float* sorted = PSacc + N_SZ;
    unsigned short* lo = (unsigned short*)(sorted + B_SZ);
    unsigned short* hi = lo + B_SZ;
    unsigned int* cnt = (unsigned int*)(hi + B_SZ);

    prep_kernel<<<dim3(N_SZ + 8), dim3(256), 0, stream>>>(feats, labels, Hp, sorted, lo, hi, Uacc, cnt);
    rank_kernel<<<dim3(B_SZ), dim3(256), 0, stream>>>(labels, sorted, lo, hi, RkT);
    main_kernel<<<dim3(32, 32), dim3(256), 0, stream>>>(Hp, labels, RkT, Uacc, Wacc, PSacc, cnt, out);
}

// Round 7
// 215.056 us; speedup vs baseline: 1.3778x; 1.2706x over previous
//
#include <hip/hip_runtime.h>
#include <math.h>

#define B_SZ 2048
#define N_SZ 4096
#define D_SZ 512
#define INV_T 14.285714285714286f
#define KC 0.3989422804014327f
#define BK 32

typedef __bf16 bf16x8 __attribute__((ext_vector_type(8)));
typedef __bf16 bf16x2 __attribute__((ext_vector_type(2)));
typedef float f32x4 __attribute__((ext_vector_type(4)));

// feats row i (view-major concat): v = i>>11, b = i&2047, src row = b*2+v
__device__ __forceinline__ long long frow(int i) {
    return (long long)(((i & (B_SZ - 1)) << 1) | (i >> 11)) * D_SZ;
}

// ---------------- Kernel 1: prep = conv + sort + zero-init (one dispatch) ----
__global__ __launch_bounds__(256) void prep_kernel(const float* __restrict__ feats,
                                                   const float* __restrict__ labels,
                                                   __bf16* __restrict__ Hp,
                                                   float* __restrict__ sorted,
                                                   unsigned short* __restrict__ lo,
                                                   unsigned short* __restrict__ hi,
                                                   float* __restrict__ accz) {
    __shared__ float lv[B_SZ];
    const int bid = blockIdx.x;
    const int t = threadIdx.x;
    if (bid < N_SZ) {
        const float2 v = *reinterpret_cast<const float2*>(&feats[frow(bid) + 2 * t]);
        bf16x2 hh = {(__bf16)v.x, (__bf16)v.y};
        *reinterpret_cast<bf16x2*>(&Hp[(size_t)bid * D_SZ + 2 * t]) = hh;
        if (bid < 48) accz[bid * 256 + t] = 0.f;   // zero Uacc/Wacc/PSacc (12288 floats)
        return;
    }
    // ---- sort section (blocks N_SZ..N_SZ+7) ----
#pragma unroll
    for (int s = 0; s < 8; ++s) lv[t + 256 * s] = labels[t + 256 * s];
    const int a = (bid - N_SZ) * 256 + t;
    const float la = labels[a];
    __syncthreads();
    int lt = 0, le = 0, tlo = 0;
    for (int c4 = 0; c4 < B_SZ / 4; ++c4) {
        float4 v = reinterpret_cast<const float4*>(lv)[c4];
        const float vv[4] = {v.x, v.y, v.z, v.w};
#pragma unroll
        for (int e = 0; e < 4; ++e) {
            lt += (vv[e] < la) ? 1 : 0;
            le += (vv[e] <= la) ? 1 : 0;
            tlo += (vv[e] == la && (4 * c4 + e) < a) ? 1 : 0;
        }
    }
    sorted[lt + tlo] = la;
    lo[a] = (unsigned short)lt;
    hi[a] = (unsigned short)le;
}

// ---------------- Kernel 2: TRANSPOSED rank table, one binary search --------
// RkT[a][b] = B - #{c: |l_b-l_c| <= |l_b-l_a|}
__global__ __launch_bounds__(256) void rank_kernel(const float* __restrict__ labels,
                                                   const float* __restrict__ sorted,
                                                   const unsigned short* __restrict__ lo,
                                                   const unsigned short* __restrict__ hi,
                                                   unsigned short* __restrict__ RkT) {
    __shared__ float Ls[B_SZ];
    const int a = blockIdx.x;
    const int t = threadIdx.x;
#pragma unroll
    for (int s = 0; s < 8; ++s) Ls[t + 256 * s] = sorted[t + 256 * s];
    const float la = labels[a];
    const int loa = (int)lo[a];
    const int hia = (int)hi[a];
    float x[8];
    int p[8];
    bool inc[8];
#pragma unroll
    for (int s = 0; s < 8; ++s) {
        const float lb = labels[t + 256 * s];
        const float ts = fabsf(lb - la);
        inc[s] = (la <= lb);
        x[s] = inc[s] ? (lb + ts) : (lb - ts);
        p[s] = 0;
    }
    __syncthreads();
#pragma unroll
    for (int step = B_SZ; step; step >>= 1) {
#pragma unroll
        for (int s = 0; s < 8; ++s) {
            const unsigned q = (unsigned)(p[s] + step - 1);
            const float Lq = Ls[q & (B_SZ - 1)];
            const bool cond = (Lq < x[s]) || (Lq == x[s] && inc[s]);
            if (q < B_SZ && cond) p[s] += step;
        }
    }
#pragma unroll
    for (int s = 0; s < 8; ++s) {
        const int inner = inc[s] ? (p[s] - loa) : (hia - p[s]);
        RkT[(size_t)a * B_SZ + t + 256 * s] = (unsigned short)(B_SZ - inner);
    }
}

// ---------------- Kernel 3: MFMA bf16 GEMM, double-buffered single-barrier --
// 128x128 tile/block, 4 waves each 64x64 (4x4 of 16x16x32 mfma), S ~= H*H^T.
// One __syncthreads per kt: loads for kt+1 are issued after the barrier and
// stay in flight for the whole compute phase of kt (drained at next barrier).
__global__ __launch_bounds__(256) void main_kernel(const __bf16* __restrict__ Hp,
                                                   const float* __restrict__ labels,
                                                   const unsigned short* __restrict__ RkT,
                                                   float* __restrict__ Uacc,
                                                   float* __restrict__ Wacc,
                                                   float* __restrict__ PSacc) {
    __shared__ __bf16 S[2][2][128 * BK];   // [buf][tile 0=A(i),1=B(j)] : 8 KB each
    __shared__ float sli[128], slj[128];

    const int t = threadIdx.x;
    const int w = t >> 6;           // wave 0..3
    const int l = t & 63;
    const int it = blockIdx.y * 128;
    const int jt = blockIdx.x * 128;

    if (t < 128) sli[t] = labels[(it + t) & (B_SZ - 1)];
    else slj[t - 128] = labels[(jt + t - 128) & (B_SZ - 1)];

    // --- staging: wave w fills half (w&1) of tile (w>>1); 0=A(i) 1=B(j) ---
    const int tileidx = w >> 1;
    const int half = w & 1;
    const int tb = tileidx ? jt : it;
    const int gblk = (l & 3) ^ ((l >> 3) & 3);      // XOR-swizzled 16B block
    const __bf16* gbase = Hp + (size_t)(tb + half * 64 + (l >> 2)) * D_SZ + gblk * 8;
    const int tileoff = (half * 64) * BK;

    // --- fragment mapping (verified m91, NT GEMM) ---
    const int lr = l & 15;
    const int quad = l >> 4;
    const int swz = (lr >> 1) & 3;
    const int wy = w >> 1, wx = w & 1;
    const int aoff = (wy * 64 + lr) * BK + ((quad ^ swz) * 8);
    const int boff = (wx * 64 + lr) * BK + ((quad ^ swz) * 8);

    f32x4 acc[4][4];
#pragma unroll
    for (int mi = 0; mi < 4; ++mi)
#pragma unroll
        for (int nj = 0; nj < 4; ++nj) acc[mi][nj] = {0.f, 0.f, 0.f, 0.f};

    // prologue: stage kt=0 into buf 0
    {
        __bf16* dst = S[0][tileidx] + tileoff;
#pragma unroll
        for (int q = 0; q < 4; ++q) {
            __builtin_amdgcn_global_load_lds(
                (const __attribute__((address_space(1))) void*)(gbase + (size_t)q * 16 * D_SZ),
                (__attribute__((address_space(3))) void*)(dst + q * 16 * BK + l * 8),
                16, 0, 0);
        }
    }

    for (int kt = 0; kt < D_SZ / BK; ++kt) {
        const int cur = kt & 1;
        __syncthreads();   // drains vmcnt -> buf[cur] ready; prior reads of buf[cur^1] done
        if (kt + 1 < D_SZ / BK) {
            const __bf16* g = gbase + (kt + 1) * BK;
            __bf16* dst = S[cur ^ 1][tileidx] + tileoff;
#pragma unroll
            for (int q = 0; q < 4; ++q) {
                __builtin_amdgcn_global_load_lds(
                    (const __attribute__((address_space(1))) void*)(g + (size_t)q * 16 * D_SZ),
                    (__attribute__((address_space(3))) void*)(dst + q * 16 * BK + l * 8),
                    16, 0, 0);
            }
        }
        bf16x8 bh[4];
#pragma unroll
        for (int nj = 0; nj < 4; ++nj)
            bh[nj] = *reinterpret_cast<const bf16x8*>(&S[cur][1][boff + nj * 16 * BK]);
#pragma unroll
        for (int mi = 0; mi < 4; ++mi) {
            bf16x8 ah = *reinterpret_cast<const bf16x8*>(&S[cur][0][aoff + mi * 16 * BK]);
#pragma unroll
            for (int nj = 0; nj < 4; ++nj)
                acc[mi][nj] = __builtin_amdgcn_mfma_f32_16x16x32_bf16(ah, bh[nj], acc[mi][nj], 0, 0, 0);
        }
    }

    // --- fused epilogue: D[row=quad*4+reg][col=lr]; RkT reads coalesced ---
    float rw[16], rp[16], ru[16];
#pragma unroll
    for (int x = 0; x < 16; ++x) { rw[x] = 0.f; rp[x] = 0.f; ru[x] = 0.f; }

    const int jcol = wx * 64 + lr;
    const int irow0 = wy * 64 + quad * 4;
#pragma unroll
    for (int nj = 0; nj < 4; ++nj) {
        const int j_g = jt + jcol + nj * 16;
        const int jb = j_g & (B_SZ - 1);
        const float lj = slj[jcol + nj * 16];
#pragma unroll
        for (int mi = 0; mi < 4; ++mi) {
#pragma unroll
            for (int reg = 0; reg < 4; ++reg) {
                const int i_g = it + irow0 + mi * 16 + reg;
                const int ib = i_g & (B_SZ - 1);
                const float rkv = (float)RkT[(size_t)ib * B_SZ + jb];
                if (i_g != j_g) {
                    const float s = acc[mi][nj][reg] * INV_T;
                    const float dl = sli[irow0 + mi * 16 + reg] - lj;
                    const float msk = __expf(dl * dl * (-0.5f)) * KC;
                    const int xx = mi * 4 + reg;
                    rw[xx] += msk;
                    rp[xx] = fmaf(msk, s, rp[xx]);
                    ru[xx] = fmaf(__expf(s - INV_T), 2.0f * rkv, ru[xx]);
                }
            }
        }
    }

#pragma unroll
    for (int xx = 0; xx < 16; ++xx) {
        float a = rw[xx], b = rp[xx], c = ru[xx];
#pragma unroll
        for (int off = 8; off >= 1; off >>= 1) {
            a += __shfl_xor(a, off, 16);
            b += __shfl_xor(b, off, 16);
            c += __shfl_xor(c, off, 16);
        }
        if (lr == 0) {
            const int mi = xx >> 2, reg = xx & 3;
            const int row = it + irow0 + mi * 16 + reg;
            atomicAdd(&Wacc[row], a);
            atomicAdd(&PSacc[row], b);
            atomicAdd(&Uacc[row], c);
        }
    }
}

// ---------------- Kernel 4: final reduce (separate dispatch, no fence) ------
__global__ __launch_bounds__(256) void finish_kernel(const float* __restrict__ Uacc,
                                                     const float* __restrict__ Wacc,
                                                     const float* __restrict__ PSacc,
                                                     float* __restrict__ out) {
    __shared__ float red[4];
    const int t = threadIdx.x;
    float sum = 0.f;
    for (int r2 = t; r2 < N_SZ; r2 += 256)
        sum += PSacc[r2] / Wacc[r2] - INV_T - logf(Uacc[r2]);
#pragma unroll
    for (int off = 32; off >= 1; off >>= 1) sum += __shfl_xor(sum, off, 64);
    if ((t & 63) == 0) red[t >> 6] = sum;
    __syncthreads();
    if (t == 0) out[0] = -(red[0] + red[1] + red[2] + red[3]) / (float)N_SZ;
}

extern "C" void kernel_launch(void* const* d_in, const int* in_sizes, int n_in,
                              void* d_out, int out_size, void* d_ws, size_t ws_size,
                              hipStream_t stream) {
    const float* feats = (const float*)d_in[0];
    const float* labels = (const float*)d_in[1];
    float* out = (float*)d_out;

    char* ws = (char*)d_ws;
    __bf16* Hp = (__bf16*)ws;                                   // 4 MB
    unsigned short* RkT = (unsigned short*)(ws + (size_t)N_SZ * D_SZ * 2);  // 8 MB
    float* Uacc = (float*)((char*)RkT + (size_t)B_SZ * B_SZ * 2);
    float* Wacc = Uacc + N_SZ;
    float* PSacc = Wacc + N_SZ;
    float* sorted = PSacc + N_SZ;
    unsigned short* lo = (unsigned short*)(sorted + B_SZ);
    unsigned short* hi = lo + B_SZ;

    prep_kernel<<<dim3(N_SZ + 8), dim3(256), 0, stream>>>(feats, labels, Hp, sorted, lo, hi, Uacc);
    rank_kernel<<<dim3(B_SZ), dim3(256), 0, stream>>>(labels, sorted, lo, hi, RkT);
    main_kernel<<<dim3(32, 32), dim3(256), 0, stream>>>(Hp, labels, RkT, Uacc, Wacc, PSacc);
    finish_kernel<<<dim3(1), dim3(256), 0, stream>>>(Uacc, Wacc, PSacc, out);
}

// Round 8
// 208.331 us; speedup vs baseline: 1.4223x; 1.0323x over previous
//
#include <hip/hip_runtime.h>
#include <math.h>

#define B_SZ 2048
#define N_SZ 4096
#define D_SZ 512
#define INV_T 14.285714285714286f
#define KC 0.3989422804014327f
#define BK 32

typedef __bf16 bf16x8 __attribute__((ext_vector_type(8)));
typedef __bf16 bf16x2 __attribute__((ext_vector_type(2)));
typedef float f32x4 __attribute__((ext_vector_type(4)));

// feats row i (view-major concat): v = i>>11, b = i&2047, src row = b*2+v
__device__ __forceinline__ long long frow(int i) {
    return (long long)(((i & (B_SZ - 1)) << 1) | (i >> 11)) * D_SZ;
}

// ---------------- Kernel 1: prep = conv + sort + zero-init (one dispatch) ----
__global__ __launch_bounds__(256) void prep_kernel(const float* __restrict__ feats,
                                                   const float* __restrict__ labels,
                                                   __bf16* __restrict__ Hp,
                                                   float* __restrict__ sorted,
                                                   unsigned short* __restrict__ lo,
                                                   unsigned short* __restrict__ hi,
                                                   float* __restrict__ accz) {
    __shared__ float lv[B_SZ];
    const int bid = blockIdx.x;
    const int t = threadIdx.x;
    if (bid < N_SZ) {
        const float2 v = *reinterpret_cast<const float2*>(&feats[frow(bid) + 2 * t]);
        bf16x2 hh = {(__bf16)v.x, (__bf16)v.y};
        *reinterpret_cast<bf16x2*>(&Hp[(size_t)bid * D_SZ + 2 * t]) = hh;
        if (bid < 48) accz[bid * 256 + t] = 0.f;   // zero Uacc/Wacc/PSacc (12288 floats)
        return;
    }
    // ---- sort section (blocks N_SZ..N_SZ+7) ----
#pragma unroll
    for (int s = 0; s < 8; ++s) lv[t + 256 * s] = labels[t + 256 * s];
    const int a = (bid - N_SZ) * 256 + t;
    const float la = labels[a];
    __syncthreads();
    int lt = 0, le = 0, tlo = 0;
    for (int c4 = 0; c4 < B_SZ / 4; ++c4) {
        float4 v = reinterpret_cast<const float4*>(lv)[c4];
        const float vv[4] = {v.x, v.y, v.z, v.w};
#pragma unroll
        for (int e = 0; e < 4; ++e) {
            lt += (vv[e] < la) ? 1 : 0;
            le += (vv[e] <= la) ? 1 : 0;
            tlo += (vv[e] == la && (4 * c4 + e) < a) ? 1 : 0;
        }
    }
    sorted[lt + tlo] = la;
    lo[a] = (unsigned short)lt;
    hi[a] = (unsigned short)le;
}

// ---------------- Kernel 2: TRANSPOSED rank table, one binary search --------
// RkT[a][b] = B - #{c: |l_b-l_c| <= |l_b-l_a|}
__global__ __launch_bounds__(256) void rank_kernel(const float* __restrict__ labels,
                                                   const float* __restrict__ sorted,
                                                   const unsigned short* __restrict__ lo,
                                                   const unsigned short* __restrict__ hi,
                                                   unsigned short* __restrict__ RkT) {
    __shared__ float Ls[B_SZ];
    const int a = blockIdx.x;
    const int t = threadIdx.x;
#pragma unroll
    for (int s = 0; s < 8; ++s) Ls[t + 256 * s] = sorted[t + 256 * s];
    const float la = labels[a];
    const int loa = (int)lo[a];
    const int hia = (int)hi[a];
    float x[8];
    int p[8];
    bool inc[8];
#pragma unroll
    for (int s = 0; s < 8; ++s) {
        const float lb = labels[t + 256 * s];
        const float ts = fabsf(lb - la);
        inc[s] = (la <= lb);
        x[s] = inc[s] ? (lb + ts) : (lb - ts);
        p[s] = 0;
    }
    __syncthreads();
#pragma unroll
    for (int step = B_SZ; step; step >>= 1) {
#pragma unroll
        for (int s = 0; s < 8; ++s) {
            const unsigned q = (unsigned)(p[s] + step - 1);
            const float Lq = Ls[q & (B_SZ - 1)];
            const bool cond = (Lq < x[s]) || (Lq == x[s] && inc[s]);
            if (q < B_SZ && cond) p[s] += step;
        }
    }
#pragma unroll
    for (int s = 0; s < 8; ++s) {
        const int inner = inc[s] ? (p[s] - loa) : (hia - p[s]);
        RkT[(size_t)a * B_SZ + t + 256 * s] = (unsigned short)(B_SZ - inner);
    }
}

// ---------------- Kernel 3: MFMA bf16 GEMM, dbuf + XCD supertile swizzle ----
// 128x128 tile/block. 1D grid; n&7 selects an XCD-coherent 8x16-tile supertile
// so each XCD's hot Hp working set is (8+16)*128KB = 3MB < 4MB L2.
// RkT epilogue reads are non-temporal (pure stream, no reuse) to stop them
// evicting Hp from L2 (R6 diagnosis: 8.6MB of Hp HBM re-reads = thrash).
__global__ __launch_bounds__(256) void main_kernel(const __bf16* __restrict__ Hp,
                                                   const float* __restrict__ labels,
                                                   const unsigned short* __restrict__ RkT,
                                                   float* __restrict__ Uacc,
                                                   float* __restrict__ Wacc,
                                                   float* __restrict__ PSacc) {
    __shared__ __bf16 S[2][2][128 * BK];   // [buf][tile 0=A(i),1=B(j)] : 8 KB each
    __shared__ float sli[128], slj[128];

    const int t = threadIdx.x;
    const int w = t >> 6;           // wave 0..3
    const int l = t & 63;

    // XCD supertile decode: xcd k gets i-tiles [(k&3)*8, +8), j-tiles [(k>>2)*16, +16)
    const int n = blockIdx.x;
    const int k8 = n & 7;
    const int s2 = n >> 3;
    const int it = ((k8 & 3) * 8 + (s2 & 7)) * 128;
    const int jt = ((k8 >> 2) * 16 + (s2 >> 3)) * 128;

    if (t < 128) sli[t] = labels[(it + t) & (B_SZ - 1)];
    else slj[t - 128] = labels[(jt + t - 128) & (B_SZ - 1)];

    // --- staging: wave w fills half (w&1) of tile (w>>1); 0=A(i) 1=B(j) ---
    const int tileidx = w >> 1;
    const int half = w & 1;
    const int tb = tileidx ? jt : it;
    const int gblk = (l & 3) ^ ((l >> 3) & 3);      // XOR-swizzled 16B block
    const __bf16* gbase = Hp + (size_t)(tb + half * 64 + (l >> 2)) * D_SZ + gblk * 8;
    const int tileoff = (half * 64) * BK;

    // --- fragment mapping (verified m91, NT GEMM) ---
    const int lr = l & 15;
    const int quad = l >> 4;
    const int swz = (lr >> 1) & 3;
    const int wy = w >> 1, wx = w & 1;
    const int aoff = (wy * 64 + lr) * BK + ((quad ^ swz) * 8);
    const int boff = (wx * 64 + lr) * BK + ((quad ^ swz) * 8);

    f32x4 acc[4][4];
#pragma unroll
    for (int mi = 0; mi < 4; ++mi)
#pragma unroll
        for (int nj = 0; nj < 4; ++nj) acc[mi][nj] = {0.f, 0.f, 0.f, 0.f};

    // prologue: stage kt=0 into buf 0
    {
        __bf16* dst = S[0][tileidx] + tileoff;
#pragma unroll
        for (int q = 0; q < 4; ++q) {
            __builtin_amdgcn_global_load_lds(
                (const __attribute__((address_space(1))) void*)(gbase + (size_t)q * 16 * D_SZ),
                (__attribute__((address_space(3))) void*)(dst + q * 16 * BK + l * 8),
                16, 0, 0);
        }
    }

    for (int kt = 0; kt < D_SZ / BK; ++kt) {
        const int cur = kt & 1;
        __syncthreads();   // drains vmcnt -> buf[cur] ready; prior reads of buf[cur^1] done
        if (kt + 1 < D_SZ / BK) {
            const __bf16* g = gbase + (kt + 1) * BK;
            __bf16* dst = S[cur ^ 1][tileidx] + tileoff;
#pragma unroll
            for (int q = 0; q < 4; ++q) {
                __builtin_amdgcn_global_load_lds(
                    (const __attribute__((address_space(1))) void*)(g + (size_t)q * 16 * D_SZ),
                    (__attribute__((address_space(3))) void*)(dst + q * 16 * BK + l * 8),
                    16, 0, 0);
            }
        }
        bf16x8 bh[4];
#pragma unroll
        for (int nj = 0; nj < 4; ++nj)
            bh[nj] = *reinterpret_cast<const bf16x8*>(&S[cur][1][boff + nj * 16 * BK]);
#pragma unroll
        for (int mi = 0; mi < 4; ++mi) {
            bf16x8 ah = *reinterpret_cast<const bf16x8*>(&S[cur][0][aoff + mi * 16 * BK]);
#pragma unroll
            for (int nj = 0; nj < 4; ++nj)
                acc[mi][nj] = __builtin_amdgcn_mfma_f32_16x16x32_bf16(ah, bh[nj], acc[mi][nj], 0, 0, 0);
        }
    }

    // --- fused epilogue: D[row=quad*4+reg][col=lr]; RkT reads coalesced + nt ---
    float rw[16], rp[16], ru[16];
#pragma unroll
    for (int x = 0; x < 16; ++x) { rw[x] = 0.f; rp[x] = 0.f; ru[x] = 0.f; }

    const int jcol = wx * 64 + lr;
    const int irow0 = wy * 64 + quad * 4;
#pragma unroll
    for (int nj = 0; nj < 4; ++nj) {
        const int j_g = jt + jcol + nj * 16;
        const int jb = j_g & (B_SZ - 1);
        const float lj = slj[jcol + nj * 16];
#pragma unroll
        for (int mi = 0; mi < 4; ++mi) {
#pragma unroll
            for (int reg = 0; reg < 4; ++reg) {
                const int i_g = it + irow0 + mi * 16 + reg;
                const int ib = i_g & (B_SZ - 1);
                const unsigned short rk_u =
                    __builtin_nontemporal_load(&RkT[(size_t)ib * B_SZ + jb]);
                const float rkv = (float)rk_u;
                if (i_g != j_g) {
                    const float s = acc[mi][nj][reg] * INV_T;
                    const float dl = sli[irow0 + mi * 16 + reg] - lj;
                    const float msk = __expf(dl * dl * (-0.5f)) * KC;
                    const int xx = mi * 4 + reg;
                    rw[xx] += msk;
                    rp[xx] = fmaf(msk, s, rp[xx]);
                    ru[xx] = fmaf(__expf(s - INV_T), 2.0f * rkv, ru[xx]);
                }
            }
        }
    }

#pragma unroll
    for (int xx = 0; xx < 16; ++xx) {
        float a = rw[xx], b = rp[xx], c = ru[xx];
#pragma unroll
        for (int off = 8; off >= 1; off >>= 1) {
            a += __shfl_xor(a, off, 16);
            b += __shfl_xor(b, off, 16);
            c += __shfl_xor(c, off, 16);
        }
        if (lr == 0) {
            const int mi = xx >> 2, reg = xx & 3;
            const int row = it + irow0 + mi * 16 + reg;
            atomicAdd(&Wacc[row], a);
            atomicAdd(&PSacc[row], b);
            atomicAdd(&Uacc[row], c);
        }
    }
}

// ---------------- Kernel 4: final reduce (separate dispatch, no fence) ------
__global__ __launch_bounds__(256) void finish_kernel(const float* __restrict__ Uacc,
                                                     const float* __restrict__ Wacc,
                                                     const float* __restrict__ PSacc,
                                                     float* __restrict__ out) {
    __shared__ float red[4];
    const int t = threadIdx.x;
    float sum = 0.f;
    for (int r2 = t; r2 < N_SZ; r2 += 256)
        sum += PSacc[r2] / Wacc[r2] - INV_T - logf(Uacc[r2]);
#pragma unroll
    for (int off = 32; off >= 1; off >>= 1) sum += __shfl_xor(sum, off, 64);
    if ((t & 63) == 0) red[t >> 6] = sum;
    __syncthreads();
    if (t == 0) out[0] = -(red[0] + red[1] + red[2] + red[3]) / (float)N_SZ;
}

extern "C" void kernel_launch(void* const* d_in, const int* in_sizes, int n_in,
                              void* d_out, int out_size, void* d_ws, size_t ws_size,
                              hipStream_t stream) {
    const float* feats = (const float*)d_in[0];
    const float* labels = (const float*)d_in[1];
    float* out = (float*)d_out;

    char* ws = (char*)d_ws;
    __bf16* Hp = (__bf16*)ws;                                   // 4 MB
    unsigned short* RkT = (unsigned short*)(ws + (size_t)N_SZ * D_SZ * 2);  // 8 MB
    float* Uacc = (float*)((char*)RkT + (size_t)B_SZ * B_SZ * 2);
    float* Wacc = Uacc + N_SZ;
    float* PSacc = Wacc + N_SZ;
    float* sorted = PSacc + N_SZ;
    unsigned short* lo = (unsigned short*)(sorted + B_SZ);
    unsigned short* hi = lo + B_SZ;

    prep_kernel<<<dim3(N_SZ + 8), dim3(256), 0, stream>>>(feats, labels, Hp, sorted, lo, hi, Uacc);
    rank_kernel<<<dim3(B_SZ), dim3(256), 0, stream>>>(labels, sorted, lo, hi, RkT);
    main_kernel<<<dim3(1024), dim3(256), 0, stream>>>(Hp, labels, RkT, Uacc, Wacc, PSacc);
    finish_kernel<<<dim3(1), dim3(256), 0, stream>>>(Uacc, Wacc, PSacc, out);
}

// Round 9
// 135.905 us; speedup vs baseline: 2.1803x; 1.5329x over previous
//
#include <hip/hip_runtime.h>
#include <math.h>

#define B_SZ 2048
#define N_SZ 4096
#define D_SZ 512
#define INV_T 14.285714285714286f
#define KC 0.3989422804014327f
#define BK 32

typedef __bf16 bf16x8 __attribute__((ext_vector_type(8)));
typedef __bf16 bf16x2 __attribute__((ext_vector_type(2)));
typedef float f32x4 __attribute__((ext_vector_type(4)));

// feats row i (view-major concat): v = i>>11, b = i&2047, src row = b*2+v
__device__ __forceinline__ long long frow(int i) {
    return (long long)(((i & (B_SZ - 1)) << 1) | (i >> 11)) * D_SZ;
}

// ---------------- Kernel 1: prep = conv + parallel sort + zero-init ---------
// blocks 0..4095: fp32->bf16 row conv (+ blocks 0..47 zero accs)
// blocks 4096..4607: counting-sort, ONE WAVE PER LABEL (R7: 8-block serial
// tail ran 60us on 8 CUs; now 512 blocks x 4 waves, ~2us)
__global__ __launch_bounds__(256) void prep_kernel(const float* __restrict__ feats,
                                                   const float* __restrict__ labels,
                                                   __bf16* __restrict__ Hp,
                                                   float* __restrict__ sorted,
                                                   unsigned short* __restrict__ lo,
                                                   unsigned short* __restrict__ hi,
                                                   float* __restrict__ accz) {
    __shared__ float lv[B_SZ];
    const int bid = blockIdx.x;
    const int t = threadIdx.x;
    if (bid < N_SZ) {
        const float2 v = *reinterpret_cast<const float2*>(&feats[frow(bid) + 2 * t]);
        bf16x2 hh = {(__bf16)v.x, (__bf16)v.y};
        *reinterpret_cast<bf16x2*>(&Hp[(size_t)bid * D_SZ + 2 * t]) = hh;
        if (bid < 48) accz[bid * 256 + t] = 0.f;   // zero Uacc/Wacc/PSacc
        return;
    }
    // ---- sort section: block handles 4 labels, wave w -> label a ----
#pragma unroll
    for (int s = 0; s < 8; ++s) lv[t + 256 * s] = labels[t + 256 * s];
    __syncthreads();
    const int w = t >> 6, l = t & 63;
    const int a = (bid - N_SZ) * 4 + w;
    const float la = lv[a];
    int lt = 0, le = 0, tlo = 0;
#pragma unroll
    for (int k = 0; k < B_SZ / 64; ++k) {
        const int c = l + 64 * k;
        const float lc = lv[c];
        lt += (lc < la) ? 1 : 0;
        le += (lc <= la) ? 1 : 0;
        tlo += (lc == la && c < a) ? 1 : 0;
    }
#pragma unroll
    for (int off = 32; off >= 1; off >>= 1) {
        lt += __shfl_xor(lt, off, 64);
        le += __shfl_xor(le, off, 64);
        tlo += __shfl_xor(tlo, off, 64);
    }
    if (l == 0) {
        sorted[lt + tlo] = la;
        lo[a] = (unsigned short)lt;
        hi[a] = (unsigned short)le;
    }
}

// ---------------- Kernel 2: TRANSPOSED rank table, one binary search --------
// RkT[a][b] = B - #{c: |l_b-l_c| <= |l_b-l_a|}
__global__ __launch_bounds__(256) void rank_kernel(const float* __restrict__ labels,
                                                   const float* __restrict__ sorted,
                                                   const unsigned short* __restrict__ lo,
                                                   const unsigned short* __restrict__ hi,
                                                   unsigned short* __restrict__ RkT) {
    __shared__ float Ls[B_SZ];
    const int a = blockIdx.x;
    const int t = threadIdx.x;
#pragma unroll
    for (int s = 0; s < 8; ++s) Ls[t + 256 * s] = sorted[t + 256 * s];
    const float la = labels[a];
    const int loa = (int)lo[a];
    const int hia = (int)hi[a];
    float x[8];
    int p[8];
    bool inc[8];
#pragma unroll
    for (int s = 0; s < 8; ++s) {
        const float lb = labels[t + 256 * s];
        const float ts = fabsf(lb - la);
        inc[s] = (la <= lb);
        x[s] = inc[s] ? (lb + ts) : (lb - ts);
        p[s] = 0;
    }
    __syncthreads();
#pragma unroll
    for (int step = B_SZ; step; step >>= 1) {
#pragma unroll
        for (int s = 0; s < 8; ++s) {
            const unsigned q = (unsigned)(p[s] + step - 1);
            const float Lq = Ls[q & (B_SZ - 1)];
            const bool cond = (Lq < x[s]) || (Lq == x[s] && inc[s]);
            if (q < B_SZ && cond) p[s] += step;
        }
    }
#pragma unroll
    for (int s = 0; s < 8; ++s) {
        const int inner = inc[s] ? (p[s] - loa) : (hia - p[s]);
        RkT[(size_t)a * B_SZ + t + 256 * s] = (unsigned short)(B_SZ - inner);
    }
}

// ---------------- Kernel 3: MFMA GEMM + LDS-staged RkT epilogue -------------
// 128x128 tile/block, dbuf K-loop, XCD supertile swizzle. After the K-loop the
// 32KB dbuf is dead; DMA the block's 128x128 RkT subtile into it (overlapped
// with the rk-independent epilogue half), then read u16 from LDS.
__global__ __launch_bounds__(256) void main_kernel(const __bf16* __restrict__ Hp,
                                                   const float* __restrict__ labels,
                                                   const unsigned short* __restrict__ RkT,
                                                   float* __restrict__ Uacc,
                                                   float* __restrict__ Wacc,
                                                   float* __restrict__ PSacc) {
    __shared__ __bf16 S[2][2][128 * BK];   // [buf][tile 0=A,1=B]: 8 KB each; 32 KB total
    __shared__ float sli[128], slj[128];

    const int t = threadIdx.x;
    const int w = t >> 6;           // wave 0..3
    const int l = t & 63;

    // XCD supertile decode: xcd k gets i-tiles [(k&3)*8,+8), j-tiles [(k>>2)*16,+16)
    const int n = blockIdx.x;
    const int k8 = n & 7;
    const int s2 = n >> 3;
    const int it = ((k8 & 3) * 8 + (s2 & 7)) * 128;
    const int jt = ((k8 >> 2) * 16 + (s2 >> 3)) * 128;

    if (t < 128) sli[t] = labels[(it + t) & (B_SZ - 1)];
    else slj[t - 128] = labels[(jt + t - 128) & (B_SZ - 1)];

    // --- staging: wave w fills half (w&1) of tile (w>>1); 0=A(i) 1=B(j) ---
    const int tileidx = w >> 1;
    const int half = w & 1;
    const int tb = tileidx ? jt : it;
    const int gblk = (l & 3) ^ ((l >> 3) & 3);      // XOR-swizzled 16B block
    const __bf16* gbase = Hp + (size_t)(tb + half * 64 + (l >> 2)) * D_SZ + gblk * 8;
    const int tileoff = (half * 64) * BK;

    // --- fragment mapping (verified m91, NT GEMM) ---
    const int lr = l & 15;
    const int quad = l >> 4;
    const int swz = (lr >> 1) & 3;
    const int wy = w >> 1, wx = w & 1;
    const int aoff = (wy * 64 + lr) * BK + ((quad ^ swz) * 8);
    const int boff = (wx * 64 + lr) * BK + ((quad ^ swz) * 8);

    f32x4 acc[4][4];
#pragma unroll
    for (int mi = 0; mi < 4; ++mi)
#pragma unroll
        for (int nj = 0; nj < 4; ++nj) acc[mi][nj] = {0.f, 0.f, 0.f, 0.f};

    // prologue: stage kt=0 into buf 0
    {
        __bf16* dst = S[0][tileidx] + tileoff;
#pragma unroll
        for (int q = 0; q < 4; ++q) {
            __builtin_amdgcn_global_load_lds(
                (const __attribute__((address_space(1))) void*)(gbase + (size_t)q * 16 * D_SZ),
                (__attribute__((address_space(3))) void*)(dst + q * 16 * BK + l * 8),
                16, 0, 0);
        }
    }

    for (int kt = 0; kt < D_SZ / BK; ++kt) {
        const int cur = kt & 1;
        __syncthreads();   // buf[cur] DMA drained; prior reads of buf[cur^1] done
        if (kt + 1 < D_SZ / BK) {
            const __bf16* g = gbase + (kt + 1) * BK;
            __bf16* dst = S[cur ^ 1][tileidx] + tileoff;
#pragma unroll
            for (int q = 0; q < 4; ++q) {
                __builtin_amdgcn_global_load_lds(
                    (const __attribute__((address_space(1))) void*)(g + (size_t)q * 16 * D_SZ),
                    (__attribute__((address_space(3))) void*)(dst + q * 16 * BK + l * 8),
                    16, 0, 0);
            }
        }
        bf16x8 bh[4];
#pragma unroll
        for (int nj = 0; nj < 4; ++nj)
            bh[nj] = *reinterpret_cast<const bf16x8*>(&S[cur][1][boff + nj * 16 * BK]);
#pragma unroll
        for (int mi = 0; mi < 4; ++mi) {
            bf16x8 ah = *reinterpret_cast<const bf16x8*>(&S[cur][0][aoff + mi * 16 * BK]);
#pragma unroll
            for (int nj = 0; nj < 4; ++nj)
                acc[mi][nj] = __builtin_amdgcn_mfma_f32_16x16x32_bf16(ah, bh[nj], acc[mi][nj], 0, 0, 0);
        }
    }

    // --- epilogue phase 0: DMA this block's RkT subtile into the dead dbuf ---
    __syncthreads();   // all frag reads of S done
    unsigned short* rkLds = (unsigned short*)&S[0][0][0];   // 128 rows x 128 u16 (256B)
    {
        const int rkrow0 = it & (B_SZ - 1);
        const int jb0 = jt & (B_SZ - 1);
        // wave w covers rows [w*32, w*32+32); each instr: 4 rows x 256B = 1KB
        const unsigned short* gsrc = RkT + (size_t)(rkrow0 + w * 32) * B_SZ + jb0;
#pragma unroll
        for (int q = 0; q < 8; ++q) {
            __builtin_amdgcn_global_load_lds(
                (const __attribute__((address_space(1))) void*)(gsrc + (size_t)(q * 4 + (l >> 4)) * B_SZ + (l & 15) * 8),
                (__attribute__((address_space(3))) void*)(rkLds + (w * 32 + q * 4) * 128 + l * 8),
                16, 0, 0);
        }
    }

    // --- epilogue phase 1 (rk-independent, overlaps DMA): mask & alignment ---
    float rw[16], rp[16];
#pragma unroll
    for (int x = 0; x < 16; ++x) { rw[x] = 0.f; rp[x] = 0.f; }
    const int jcol = wx * 64 + lr;
    const int irow0 = wy * 64 + quad * 4;
#pragma unroll
    for (int nj = 0; nj < 4; ++nj) {
        const int j_g = jt + jcol + nj * 16;
        const float lj = slj[jcol + nj * 16];
#pragma unroll
        for (int mi = 0; mi < 4; ++mi) {
#pragma unroll
            for (int reg = 0; reg < 4; ++reg) {
                const int i_g = it + irow0 + mi * 16 + reg;
                if (i_g != j_g) {
                    const float s = acc[mi][nj][reg] * INV_T;
                    const float dl = sli[irow0 + mi * 16 + reg] - lj;
                    const float msk = __expf(dl * dl * (-0.5f)) * KC;
                    const int xx = mi * 4 + reg;
                    rw[xx] += msk;
                    rp[xx] = fmaf(msk, s, rp[xx]);
                }
            }
        }
    }

    __syncthreads();   // RkT DMA drained

    // --- epilogue phase 2: uniformity (rk from LDS) ---
    float ru[16];
#pragma unroll
    for (int x = 0; x < 16; ++x) ru[x] = 0.f;
#pragma unroll
    for (int nj = 0; nj < 4; ++nj) {
        const int j_g = jt + jcol + nj * 16;
        const int jcl = jcol + nj * 16;
#pragma unroll
        for (int mi = 0; mi < 4; ++mi) {
#pragma unroll
            for (int reg = 0; reg < 4; ++reg) {
                const int i_g = it + irow0 + mi * 16 + reg;
                if (i_g != j_g) {
                    const float s = acc[mi][nj][reg] * INV_T;
                    const float rkv = (float)rkLds[(irow0 + mi * 16 + reg) * 128 + jcl];
                    ru[mi * 4 + reg] = fmaf(__expf(s - INV_T), 2.0f * rkv, ru[mi * 4 + reg]);
                }
            }
        }
    }

#pragma unroll
    for (int xx = 0; xx < 16; ++xx) {
        float a = rw[xx], b = rp[xx], c = ru[xx];
#pragma unroll
        for (int off = 8; off >= 1; off >>= 1) {
            a += __shfl_xor(a, off, 16);
            b += __shfl_xor(b, off, 16);
            c += __shfl_xor(c, off, 16);
        }
        if (lr == 0) {
            const int mi = xx >> 2, reg = xx & 3;
            const int row = it + irow0 + mi * 16 + reg;
            atomicAdd(&Wacc[row], a);
            atomicAdd(&PSacc[row], b);
            atomicAdd(&Uacc[row], c);
        }
    }
}

// ---------------- Kernel 4: final reduce ----------------
__global__ __launch_bounds__(256) void finish_kernel(const float* __restrict__ Uacc,
                                                     const float* __restrict__ Wacc,
                                                     const float* __restrict__ PSacc,
                                                     float* __restrict__ out) {
    __shared__ float red[4];
    const int t = threadIdx.x;
    float sum = 0.f;
    for (int r2 = t; r2 < N_SZ; r2 += 256)
        sum += PSacc[r2] / Wacc[r2] - INV_T - logf(Uacc[r2]);
#pragma unroll
    for (int off = 32; off >= 1; off >>= 1) sum += __shfl_xor(sum, off, 64);
    if ((t & 63) == 0) red[t >> 6] = sum;
    __syncthreads();
    if (t == 0) out[0] = -(red[0] + red[1] + red[2] + red[3]) / (float)N_SZ;
}

extern "C" void kernel_launch(void* const* d_in, const int* in_sizes, int n_in,
                              void* d_out, int out_size, void* d_ws, size_t ws_size,
                              hipStream_t stream) {
    const float* feats = (const float*)d_in[0];
    const float* labels = (const float*)d_in[1];
    float* out = (float*)d_out;

    char* ws = (char*)d_ws;
    __bf16* Hp = (__bf16*)ws;                                   // 4 MB
    unsigned short* RkT = (unsigned short*)(ws + (size_t)N_SZ * D_SZ * 2);  // 8 MB
    float* Uacc = (float*)((char*)RkT + (size_t)B_SZ * B_SZ * 2);
    float* Wacc = Uacc + N_SZ;
    float* PSacc = Wacc + N_SZ;
    float* sorted = PSacc + N_SZ;
    unsigned short* lo = (unsigned short*)(sorted + B_SZ);
    unsigned short* hi = lo + B_SZ;

    prep_kernel<<<dim3(N_SZ + 512), dim3(256), 0, stream>>>(feats, labels, Hp, sorted, lo, hi, Uacc);
    rank_kernel<<<dim3(B_SZ), dim3(256), 0, stream>>>(labels, sorted, lo, hi, RkT);
    main_kernel<<<dim3(1024), dim3(256), 0, stream>>>(Hp, labels, RkT, Uacc, Wacc, PSacc);
    finish_kernel<<<dim3(1), dim3(256), 0, stream>>>(Uacc, Wacc, PSacc, out);
}

// Round 10
// 134.887 us; speedup vs baseline: 2.1967x; 1.0075x over previous
//
#include <hip/hip_runtime.h>
#include <math.h>

#define B_SZ 2048
#define N_SZ 4096
#define D_SZ 512
#define INV_T 14.285714285714286f
#define KC 0.3989422804014327f
#define BK 32

typedef __bf16 bf16x8 __attribute__((ext_vector_type(8)));
typedef __bf16 bf16x2 __attribute__((ext_vector_type(2)));
typedef float f32x4 __attribute__((ext_vector_type(4)));

// feats row i (view-major concat): v = i>>11, b = i&2047, src row = b*2+v
__device__ __forceinline__ long long frow(int i) {
    return (long long)(((i & (B_SZ - 1)) << 1) | (i >> 11)) * D_SZ;
}

// ---------------- Kernel 1: prep = conv + parallel sort + zero-init ---------
__global__ __launch_bounds__(256) void prep_kernel(const float* __restrict__ feats,
                                                   const float* __restrict__ labels,
                                                   __bf16* __restrict__ Hp,
                                                   float* __restrict__ sorted,
                                                   unsigned short* __restrict__ lo,
                                                   unsigned short* __restrict__ hi,
                                                   float* __restrict__ accz) {
    __shared__ float lv[B_SZ];
    const int bid = blockIdx.x;
    const int t = threadIdx.x;
    if (bid < N_SZ) {
        const float2 v = *reinterpret_cast<const float2*>(&feats[frow(bid) + 2 * t]);
        bf16x2 hh = {(__bf16)v.x, (__bf16)v.y};
        *reinterpret_cast<bf16x2*>(&Hp[(size_t)bid * D_SZ + 2 * t]) = hh;
        if (bid < 48) accz[bid * 256 + t] = 0.f;   // zero Uacc/Wacc/PSacc
        return;
    }
    // ---- sort section: block handles 4 labels, wave w -> label a ----
#pragma unroll
    for (int s = 0; s < 8; ++s) lv[t + 256 * s] = labels[t + 256 * s];
    __syncthreads();
    const int w = t >> 6, l = t & 63;
    const int a = (bid - N_SZ) * 4 + w;
    const float la = lv[a];
    int lt = 0, le = 0, tlo = 0;
#pragma unroll
    for (int k = 0; k < B_SZ / 64; ++k) {
        const int c = l + 64 * k;
        const float lc = lv[c];
        lt += (lc < la) ? 1 : 0;
        le += (lc <= la) ? 1 : 0;
        tlo += (lc == la && c < a) ? 1 : 0;
    }
#pragma unroll
    for (int off = 32; off >= 1; off >>= 1) {
        lt += __shfl_xor(lt, off, 64);
        le += __shfl_xor(le, off, 64);
        tlo += __shfl_xor(tlo, off, 64);
    }
    if (l == 0) {
        sorted[lt + tlo] = la;
        lo[a] = (unsigned short)lt;
        hi[a] = (unsigned short)le;
    }
}

// ---------------- Kernel 2: TRANSPOSED rank table, one binary search --------
__global__ __launch_bounds__(256) void rank_kernel(const float* __restrict__ labels,
                                                   const float* __restrict__ sorted,
                                                   const unsigned short* __restrict__ lo,
                                                   const unsigned short* __restrict__ hi,
                                                   unsigned short* __restrict__ RkT) {
    __shared__ float Ls[B_SZ];
    const int a = blockIdx.x;
    const int t = threadIdx.x;
#pragma unroll
    for (int s = 0; s < 8; ++s) Ls[t + 256 * s] = sorted[t + 256 * s];
    const float la = labels[a];
    const int loa = (int)lo[a];
    const int hia = (int)hi[a];
    float x[8];
    int p[8];
    bool inc[8];
#pragma unroll
    for (int s = 0; s < 8; ++s) {
        const float lb = labels[t + 256 * s];
        const float ts = fabsf(lb - la);
        inc[s] = (la <= lb);
        x[s] = inc[s] ? (lb + ts) : (lb - ts);
        p[s] = 0;
    }
    __syncthreads();
#pragma unroll
    for (int step = B_SZ; step; step >>= 1) {
#pragma unroll
        for (int s = 0; s < 8; ++s) {
            const unsigned q = (unsigned)(p[s] + step - 1);
            const float Lq = Ls[q & (B_SZ - 1)];
            const bool cond = (Lq < x[s]) || (Lq == x[s] && inc[s]);
            if (q < B_SZ && cond) p[s] += step;
        }
    }
#pragma unroll
    for (int s = 0; s < 8; ++s) {
        const int inner = inc[s] ? (p[s] - loa) : (hia - p[s]);
        RkT[(size_t)a * B_SZ + t + 256 * s] = (unsigned short)(B_SZ - inner);
    }
}

// ---------------- Kernel 3: MFMA GEMM, tbuf distance-2, alias-local swizzle -
// 128x128 tile/block. Alias-local supertile: the 4 view-aliases of each
// (ib,jb) tile-pair run adjacently on the SAME XCD (RkT/Hp reuse is L2-local).
// K-loop: triple-buffered LDS, raw s_barrier + s_waitcnt vmcnt(4) so the
// distance-2 DMA stays in flight across two compute phases (~HBM latency).
__global__ __launch_bounds__(256) void main_kernel(const __bf16* __restrict__ Hp,
                                                   const float* __restrict__ labels,
                                                   const unsigned short* __restrict__ RkT,
                                                   float* __restrict__ Uacc,
                                                   float* __restrict__ Wacc,
                                                   float* __restrict__ PSacc) {
    __shared__ __bf16 S[3][2][128 * BK];   // [buf][tile 0=A,1=B]: 8 KB each; 48 KB
    __shared__ float sli[128], slj[128];

    const int t = threadIdx.x;
    const int w = t >> 6;           // wave 0..3
    const int l = t & 63;

    // alias-local supertile decode (bits of s2: [0]=i-alias,[1]=j-alias,
    // [2:3]=i-base-in-group, [4:6]=j-base-in-group)
    const int n = blockIdx.x;
    const int k8 = n & 7;
    const int s2 = n >> 3;
    const int ti = (k8 & 3) * 4 + ((s2 >> 2) & 3) + 16 * (s2 & 1);
    const int tj = (k8 >> 2) * 8 + ((s2 >> 4) & 7) + 16 * ((s2 >> 1) & 1);
    const int it = ti * 128, jt = tj * 128;

    if (t < 128) sli[t] = labels[(it + t) & (B_SZ - 1)];
    else slj[t - 128] = labels[(jt + t - 128) & (B_SZ - 1)];

    // --- staging geometry: wave w fills half (w&1) of tile (w>>1) ---
    const int tileidx = w >> 1;
    const int half = w & 1;
    const int tb = tileidx ? jt : it;
    const int gblk = (l & 3) ^ ((l >> 3) & 3);      // XOR-swizzled 16B block
    const __bf16* gbase = Hp + (size_t)(tb + half * 64 + (l >> 2)) * D_SZ + gblk * 8;
    const int tileoff = (half * 64) * BK;

#define STAGE(ktv, buf)                                                         \
    {                                                                           \
        const __bf16* g_ = gbase + (ktv) * BK;                                  \
        __bf16* dst_ = S[buf][tileidx] + tileoff;                               \
        _Pragma("unroll")                                                       \
        for (int q = 0; q < 4; ++q) {                                           \
            __builtin_amdgcn_global_load_lds(                                   \
                (const __attribute__((address_space(1))) void*)(g_ + (size_t)q * 16 * D_SZ), \
                (__attribute__((address_space(3))) void*)(dst_ + q * 16 * BK + l * 8),       \
                16, 0, 0);                                                      \
        }                                                                       \
    }

    // --- fragment mapping (verified m91, NT GEMM) ---
    const int lr = l & 15;
    const int quad = l >> 4;
    const int swz = (lr >> 1) & 3;
    const int wy = w >> 1, wx = w & 1;
    const int aoff = (wy * 64 + lr) * BK + ((quad ^ swz) * 8);
    const int boff = (wx * 64 + lr) * BK + ((quad ^ swz) * 8);

    f32x4 acc[4][4];
#pragma unroll
    for (int mi = 0; mi < 4; ++mi)
#pragma unroll
        for (int nj = 0; nj < 4; ++nj) acc[mi][nj] = {0.f, 0.f, 0.f, 0.f};

    // prologue: stage kt=0 -> buf0, kt=1 -> buf1 (8 DMAs outstanding/thread)
    STAGE(0, 0)
    STAGE(1, 1)

#pragma unroll
    for (int kt = 0; kt < D_SZ / BK; ++kt) {
        const int cur = kt % 3;
        // stage kt retired (oldest 4 of 8); cross-wave visibility via barrier
        if (kt < D_SZ / BK - 1) {
            asm volatile("s_waitcnt vmcnt(4)" ::: "memory");
        } else {
            asm volatile("s_waitcnt vmcnt(0)" ::: "memory");
        }
        asm volatile("s_barrier" ::: "memory");
        if (kt + 2 < D_SZ / BK) STAGE(kt + 2, (kt + 2) % 3)

        bf16x8 bh[4];
#pragma unroll
        for (int nj = 0; nj < 4; ++nj)
            bh[nj] = *reinterpret_cast<const bf16x8*>(&S[cur][1][boff + nj * 16 * BK]);
#pragma unroll
        for (int mi = 0; mi < 4; ++mi) {
            bf16x8 ah = *reinterpret_cast<const bf16x8*>(&S[cur][0][aoff + mi * 16 * BK]);
#pragma unroll
            for (int nj = 0; nj < 4; ++nj)
                acc[mi][nj] = __builtin_amdgcn_mfma_f32_16x16x32_bf16(ah, bh[nj], acc[mi][nj], 0, 0, 0);
        }
    }

    // --- epilogue phase 0: DMA this block's RkT subtile into the dead bufs ---
    __syncthreads();   // all frag reads of S done
    unsigned short* rkLds = (unsigned short*)&S[0][0][0];   // 128 x 128 u16 = 32 KB
    {
        const int rkrow0 = it & (B_SZ - 1);
        const int jb0 = jt & (B_SZ - 1);
        const unsigned short* gsrc = RkT + (size_t)(rkrow0 + w * 32) * B_SZ + jb0;
#pragma unroll
        for (int q = 0; q < 8; ++q) {
            __builtin_amdgcn_global_load_lds(
                (const __attribute__((address_space(1))) void*)(gsrc + (size_t)(q * 4 + (l >> 4)) * B_SZ + (l & 15) * 8),
                (__attribute__((address_space(3))) void*)(rkLds + (w * 32 + q * 4) * 128 + l * 8),
                16, 0, 0);
        }
    }

    // --- epilogue phase 1 (rk-independent, overlaps DMA): mask & alignment ---
    float rw[16], rp[16];
#pragma unroll
    for (int x = 0; x < 16; ++x) { rw[x] = 0.f; rp[x] = 0.f; }
    const int jcol = wx * 64 + lr;
    const int irow0 = wy * 64 + quad * 4;
#pragma unroll
    for (int nj = 0; nj < 4; ++nj) {
        const int j_g = jt + jcol + nj * 16;
        const float lj = slj[jcol + nj * 16];
#pragma unroll
        for (int mi = 0; mi < 4; ++mi) {
#pragma unroll
            for (int reg = 0; reg < 4; ++reg) {
                const int i_g = it + irow0 + mi * 16 + reg;
                if (i_g != j_g) {
                    const float s = acc[mi][nj][reg] * INV_T;
                    const float dl = sli[irow0 + mi * 16 + reg] - lj;
                    const float msk = __expf(dl * dl * (-0.5f)) * KC;
                    const int xx = mi * 4 + reg;
                    rw[xx] += msk;
                    rp[xx] = fmaf(msk, s, rp[xx]);
                }
            }
        }
    }

    __syncthreads();   // RkT DMA drained

    // --- epilogue phase 2: uniformity (rk from LDS) ---
    float ru[16];
#pragma unroll
    for (int x = 0; x < 16; ++x) ru[x] = 0.f;
#pragma unroll
    for (int nj = 0; nj < 4; ++nj) {
        const int j_g = jt + jcol + nj * 16;
        const int jcl = jcol + nj * 16;
#pragma unroll
        for (int mi = 0; mi < 4; ++mi) {
#pragma unroll
            for (int reg = 0; reg < 4; ++reg) {
                const int i_g = it + irow0 + mi * 16 + reg;
                if (i_g != j_g) {
                    const float s = acc[mi][nj][reg] * INV_T;
                    const float rkv = (float)rkLds[(irow0 + mi * 16 + reg) * 128 + jcl];
                    ru[mi * 4 + reg] = fmaf(__expf(s - INV_T), 2.0f * rkv, ru[mi * 4 + reg]);
                }
            }
        }
    }

#pragma unroll
    for (int xx = 0; xx < 16; ++xx) {
        float a = rw[xx], b = rp[xx], c = ru[xx];
#pragma unroll
        for (int off = 8; off >= 1; off >>= 1) {
            a += __shfl_xor(a, off, 16);
            b += __shfl_xor(b, off, 16);
            c += __shfl_xor(c, off, 16);
        }
        if (lr == 0) {
            const int mi = xx >> 2, reg = xx & 3;
            const int row = it + irow0 + mi * 16 + reg;
            atomicAdd(&Wacc[row], a);
            atomicAdd(&PSacc[row], b);
            atomicAdd(&Uacc[row], c);
        }
    }
#undef STAGE
}

// ---------------- Kernel 4: final reduce ----------------
__global__ __launch_bounds__(256) void finish_kernel(const float* __restrict__ Uacc,
                                                     const float* __restrict__ Wacc,
                                                     const float* __restrict__ PSacc,
                                                     float* __restrict__ out) {
    __shared__ float red[4];
    const int t = threadIdx.x;
    float sum = 0.f;
    for (int r2 = t; r2 < N_SZ; r2 += 256)
        sum += PSacc[r2] / Wacc[r2] - INV_T - logf(Uacc[r2]);
#pragma unroll
    for (int off = 32; off >= 1; off >>= 1) sum += __shfl_xor(sum, off, 64);
    if ((t & 63) == 0) red[t >> 6] = sum;
    __syncthreads();
    if (t == 0) out[0] = -(red[0] + red[1] + red[2] + red[3]) / (float)N_SZ;
}

extern "C" void kernel_launch(void* const* d_in, const int* in_sizes, int n_in,
                              void* d_out, int out_size, void* d_ws, size_t ws_size,
                              hipStream_t stream) {
    const float* feats = (const float*)d_in[0];
    const float* labels = (const float*)d_in[1];
    float* out = (float*)d_out;

    char* ws = (char*)d_ws;
    __bf16* Hp = (__bf16*)ws;                                   // 4 MB
    unsigned short* RkT = (unsigned short*)(ws + (size_t)N_SZ * D_SZ * 2);  // 8 MB
    float* Uacc = (float*)((char*)RkT + (size_t)B_SZ * B_SZ * 2);
    float* Wacc = Uacc + N_SZ;
    float* PSacc = Wacc + N_SZ;
    float* sorted = PSacc + N_SZ;
    unsigned short* lo = (unsigned short*)(sorted + B_SZ);
    unsigned short* hi = lo + B_SZ;

    prep_kernel<<<dim3(N_SZ + 512), dim3(256), 0, stream>>>(feats, labels, Hp, sorted, lo, hi, Uacc);
    rank_kernel<<<dim3(B_SZ), dim3(256), 0, stream>>>(labels, sorted, lo, hi, RkT);
    main_kernel<<<dim3(1024), dim3(256), 0, stream>>>(Hp, labels, RkT, Uacc, Wacc, PSacc);
    finish_kernel<<<dim3(1), dim3(256), 0, stream>>>(Uacc, Wacc, PSacc, out);
}